// Round 16
// baseline (71.694 us; speedup 1.0000x reference)
//
#include <hip/hip_runtime.h>
#include <float.h>

#define B_ 16
#define D_ 64
#define L_ 8192
#define K_ 512
#define NBLOCKS 512
#define TILES_PER_BLOCK 2     // 1024 tiles / 512 blocks -> 2 blocks/CU (66.5 KB LDS)
#define EPS 0.0625f           // shifted-score gap err (fp16 dot) << EPS/2

// r16 = r15 with the __half bitcast replaced by a _Float16* store (compile
// fix only; r15 design untested). Decoupled waves: xT/xAh/bestk LDS deleted;
// B-frags staged global->reg in frag layout; exact pass computes np-bitexact
// xsq in-pass; per-wave epilogue. ZERO barriers in the tile loop.
// LDS = eF 64 KB + esq 2 KB -> 2 blocks/CU, 4 waves/SIMD, waves independent.

typedef __attribute__((ext_vector_type(8))) _Float16 half8;
typedef __attribute__((ext_vector_type(4))) float    f32x4;

__device__ __forceinline__ unsigned f32_sortable(float x) {
    unsigned u = __float_as_uint(x);
    return u ^ (((int)u >> 31) | 0x80000000u);   // ascending uint == ascending float
}

__global__ __launch_bounds__(512, 2)
void vq_mfma_kernel(const float* __restrict__ X, const float* __restrict__ E,
                    float* __restrict__ out_emb, float* __restrict__ out_idx)
{
    __shared__ __align__(16) short eF[32768];    // E fp16 A-frags: [blk][kh] x 64 lanes x 8, 64 KB
    __shared__ float esq_s[K_];                  // 2 KB

    const int tid  = threadIdx.x;
    const int lane = tid & 63;
    const int wave = tid >> 6;        // 0..7
    const int lo4  = lane & 15;
    const int hi4  = lane >> 4;

    // ---- prologue (fused): coalesced E read -> esq (np sequential d-order,
    //      rounded squares) + fp16 frag scatter into eF. Bit-identical chain.
    {
        _Float16* eH = (_Float16*)eF;
        float s = 0.f;
        int code = tid;                          // 0..511
        int blk = code >> 4, c15 = code & 15;
        #pragma unroll 8
        for (int d = 0; d < D_; ++d) {
            float v = E[d * K_ + code];          // coalesced 2 KB/row
            float sq = v * v;
            asm volatile("" : "+v"(sq));         // np rounds the square first
            s = s + sq;                          // d ascending == np axis-0 order
            int kh = d >> 5, fl = ((d >> 3) & 3) * 16 + c15, j = d & 7;
            eH[((blk * 2 + kh) * 64 + fl) * 8 + j] = (_Float16)v;   // RNE cvt
        }
        esq_s[code] = s;
    }
    __syncthreads();                             // only barrier in the kernel

    for (int t = 0; t < TILES_PER_BLOCK; ++t) {
        int tile = blockIdx.x * TILES_PER_BLOCK + t;
        int b  = tile >> 6;                      // tile / 64
        int l0 = (tile & 63) << 7;               // (tile % 64) * 128
        const int token = wave * 16 + lo4;       // this lane's token (col)

        // ---- stage B-frags direct global->reg (frag layout; 64B segments) --
        half8 bh0, bh1;
        {
            const float* xb = X + ((size_t)(b * 64 + hi4 * 8)) * L_ + l0 + token;
            #pragma unroll
            for (int j = 0; j < 8; ++j) {
                bh0[j] = (_Float16)xb[(size_t)j * L_];            // d = hi4*8+j
                bh1[j] = (_Float16)xb[(size_t)(32 + j) * L_];     // d = 32+hi4*8+j
            }
        }

        // ---- main: 32 code-blocks; shifted score (es - 2*dot); reg fold ----
        float m1 = FLT_MAX, m2 = FLT_MAX;
        int   k1 = 0x7FFFFFFF;
        #pragma unroll 8
        for (int blk = 0; blk < 32; ++blk) {
            half8 ah0 = ((const half8*)eF)[(blk * 2 + 0) * 64 + lane];
            half8 ah1 = ((const half8*)eF)[(blk * 2 + 1) * 64 + lane];
            f32x4 c = {0.f, 0.f, 0.f, 0.f};
            c = __builtin_amdgcn_mfma_f32_16x16x32_f16(ah0, bh0, c, 0, 0, 0);
            c = __builtin_amdgcn_mfma_f32_16x16x32_f16(ah1, bh1, c, 0, 0, 0);
            float4 es4 = *reinterpret_cast<const float4*>(&esq_s[blk * 16 + hi4 * 4]);
            float es[4] = {es4.x, es4.y, es4.z, es4.w};
            #pragma unroll
            for (int r = 0; r < 4; ++r) {
                float sc = fmaf(-2.0f, c[r], es[r]);   // xs const/token: gap invariant
                int   cd = blk * 16 + hi4 * 4 + r;     // ascending within lane
                if (sc < m1)      { m2 = m1; m1 = sc; k1 = cd; }
                else              { m2 = fminf(m2, sc); }
            }
        }

        // ---- merge 4 hi4-copies per token (xor 16, 32) — validated logic ---
        #pragma unroll
        for (int off = 16; off < 64; off <<= 1) {
            float ov = __shfl_xor(m1, off, 64);
            int   ok = __shfl_xor(k1, off, 64);
            float o2 = __shfl_xor(m2, off, 64);
            float n2 = fminf(fminf(m2, o2), fmaxf(m1, ov));
            if (ov < m1 || (ov == m1 && ok < k1)) { m1 = ov; k1 = ok; }
            m2 = n2;
        }

        // ---- flag near-ties; wave-local exact pass (np-bitexact) ----------
        unsigned long long bal = __ballot((lane < 16) && (m2 <= m1 + EPS));
        while (bal) {
            int tk = (int)__builtin_ctzll(bal);
            bal &= bal - 1;
            // xsq in-pass: np pairwise-8 (j = lane&7, all lanes redundant)
            float xs_e;
            {
                int j = lane & 7;
                float r = 0.f;
                #pragma unroll
                for (int m = 0; m < 8; ++m) {
                    float v = X[((size_t)(b * 64 + m * 8 + j)) * L_ + l0 + wave * 16 + tk];
                    float sq = v * v;
                    asm volatile("" : "+v"(sq)); // np rounds the square first
                    r = r + sq;                  // m ascending: np r8[j] order
                }
                r = r + __shfl_xor(r, 1, 64);    // (r0+r1) ...
                r = r + __shfl_xor(r, 2, 64);    // ((r0+r1)+(r2+r3)) ...
                r = r + __shfl_xor(r, 4, 64);    // full np pairwise tree
                xs_e = r;                        // identical in each 8-lane group
            }
            // dot: lane owns codes 8*lane..+7; d-ascending fmaf (np chain)
            float d0 = 0.f, d1 = 0.f, d2 = 0.f, d3 = 0.f;
            float d4 = 0.f, d5 = 0.f, d6 = 0.f, d7 = 0.f;
            const float* Ep = E + 8 * lane;
            #pragma unroll 4
            for (int d = 0; d < 64; ++d) {
                float xv = X[((size_t)(b * 64 + d)) * L_ + l0 + wave * 16 + tk];
                float4 e0 = *reinterpret_cast<const float4*>(Ep + d * K_);
                float4 e1 = *reinterpret_cast<const float4*>(Ep + d * K_ + 4);
                d0 = fmaf(xv, e0.x, d0); d1 = fmaf(xv, e0.y, d1);
                d2 = fmaf(xv, e0.z, d2); d3 = fmaf(xv, e0.w, d3);
                d4 = fmaf(xv, e1.x, d4); d5 = fmaf(xv, e1.y, d5);
                d6 = fmaf(xv, e1.z, d6); d7 = fmaf(xv, e1.w, d7);
            }
            float4 qa = *reinterpret_cast<const float4*>(&esq_s[8 * lane]);
            float4 qb = *reinterpret_cast<const float4*>(&esq_s[8 * lane + 4]);
            float sc[8];
            sc[0] = (xs_e - 2.0f * d0) + qa.x; sc[1] = (xs_e - 2.0f * d1) + qa.y;
            sc[2] = (xs_e - 2.0f * d2) + qa.z; sc[3] = (xs_e - 2.0f * d3) + qa.w;
            sc[4] = (xs_e - 2.0f * d4) + qb.x; sc[5] = (xs_e - 2.0f * d5) + qb.y;
            sc[6] = (xs_e - 2.0f * d6) + qb.z; sc[7] = (xs_e - 2.0f * d7) + qb.w;
            unsigned long long pk = ~0ULL;
            #pragma unroll
            for (int j = 0; j < 8; ++j) {        // ascending code: first-min kept
                unsigned long long p =
                    ((unsigned long long)f32_sortable(sc[j]) << 32) |
                    (unsigned)(8 * lane + j);
                if (p < pk) pk = p;
            }
            #pragma unroll
            for (int off = 1; off < 64; off <<= 1) {
                unsigned long long o = __shfl_xor(pk, off, 64);
                if (o < pk) pk = o;
            }
            int k_ex = (int)(unsigned)(pk & 0xFFFFFFFFULL);
            if (lo4 == tk) k1 = k_ex;            // update all 4 hi4 copies
        }

        // ---- per-wave epilogue: no LDS, no barrier ------------------------
        // lane: token = wave*16+lo4, d-rows hi4*16..hi4*16+15
        {
            size_t obase = (size_t)b * 64 * L_ + l0 + token;
            #pragma unroll 4
            for (int dd = 0; dd < 16; ++dd) {
                int d = hi4 * 16 + dd;
                out_emb[obase + (size_t)d * L_] = E[d * K_ + k1];
            }
            if (hi4 == 0)
                out_idx[(size_t)b * L_ + l0 + token] = (float)k1;
        }
    }
}

extern "C" void kernel_launch(void* const* d_in, const int* in_sizes, int n_in,
                              void* d_out, int out_size, void* d_ws, size_t ws_size,
                              hipStream_t stream) {
    const float* X = (const float*)d_in[0];   // (B, D, L) fp32
    const float* E = (const float*)d_in[1];   // (D, K) fp32
    float* out     = (float*)d_out;
    float* out_emb = out;
    float* out_idx = out + (size_t)B_ * D_ * L_;
    vq_mfma_kernel<<<NBLOCKS, 512, 0, stream>>>(X, E, out_emb, out_idx);
}